// Round 20
// baseline (249.140 us; speedup 1.0000x reference)
//
#include <hip/hip_runtime.h>
#include <hip/hip_bf16.h>

typedef __attribute__((ext_vector_type(8))) __bf16 bf16x8;
typedef __attribute__((ext_vector_type(4))) __bf16 bf16x4;
typedef __attribute__((ext_vector_type(4))) float f32x4;
typedef __attribute__((ext_vector_type(16))) float f32x16;

#define MFMA16(a, b, c) __builtin_amdgcn_mfma_f32_16x16x32_bf16((a), (b), (c), 0, 0, 0)
#define MFMA32(a, b, c) __builtin_amdgcn_mfma_f32_32x32x16_bf16((a), (b), (c), 0, 0, 0)
#define LOG2E 1.4426950408889634f

static __device__ __forceinline__ float exp2_fast(float x) {
    float r; asm("v_exp_f32 %0, %1" : "=v"(r) : "v"(x)); return r;
}

__device__ __forceinline__ void gll16(const void* g, void* l) {
    __builtin_amdgcn_global_load_lds((const __attribute__((address_space(1))) void*)g,
                                     (__attribute__((address_space(3))) void*)l,
                                     16, 0, 0);
}

// ---- prep: [0,2048) bank->membf (+f32 copy if mem_out); [2048,4096) LN1(+bf16);
// ----       [4096,7168) early weight transposes; [7168,9216) mask bitpack (big only) ----
__global__ __launch_bounds__(256) void prep_kernel(const float* __restrict__ bank,
                                                   float* __restrict__ mem_out,
                                                   __bf16* __restrict__ membf,
                                                   const float* __restrict__ x,
                                                   const float* __restrict__ g,
                                                   const float* __restrict__ bta,
                                                   float* __restrict__ q_out,
                                                   __bf16* __restrict__ qbf,
                                                   const float* __restrict__ Wq,
                                                   const float* __restrict__ Wk,
                                                   const float* __restrict__ Wv,
                                                   __bf16* __restrict__ Wq_t,
                                                   __bf16* __restrict__ Wkv_t,
                                                   const unsigned char* __restrict__ mask,
                                                   unsigned int* __restrict__ mbits) {
    __shared__ float rs[4], rs2[4];
    __shared__ float tile[32][33];
    int blk = blockIdx.x;
    if (blk < 2048) {
        int i = blk * 256 + threadIdx.x;
        const float4* i4 = (const float4*)bank;
        float4* o4 = (float4*)mem_out;
        for (; i < 2097152; i += 2048 * 256) {
            float4 v = i4[i];
            if (mem_out) o4[i] = v;
            if (membf) {
                bf16x4 ob = {(__bf16)v.x, (__bf16)v.y, (__bf16)v.z, (__bf16)v.w};
                ((bf16x4*)membf)[i] = ob;
            }
        }
    } else if (blk < 4096) {
        int row = blk - 2048;
        const float4 v = ((const float4*)(x + (size_t)row * 1024))[threadIdx.x];
        float s = v.x + v.y + v.z + v.w;
        float s2 = v.x * v.x + v.y * v.y + v.z * v.z + v.w * v.w;
#pragma unroll
        for (int off = 1; off < 64; off <<= 1) {
            s += __shfl_xor(s, off);
            s2 += __shfl_xor(s2, off);
        }
        int wv = threadIdx.x >> 6;
        if ((threadIdx.x & 63) == 0) { rs[wv] = s; rs2[wv] = s2; }
        __syncthreads();
        s = rs[0] + rs[1] + rs[2] + rs[3];
        s2 = rs2[0] + rs2[1] + rs2[2] + rs2[3];
        float mean = s * (1.0f / 1024.0f);
        float var = s2 * (1.0f / 1024.0f) - mean * mean;
        float rstd = rsqrtf(var + 1e-5f);
        float4 gg = ((const float4*)g)[threadIdx.x];
        float4 bb = ((const float4*)bta)[threadIdx.x];
        float4 o;
        o.x = (v.x - mean) * rstd * gg.x + bb.x;
        o.y = (v.y - mean) * rstd * gg.y + bb.y;
        o.z = (v.z - mean) * rstd * gg.z + bb.z;
        o.w = (v.w - mean) * rstd * gg.w + bb.w;
        ((float4*)(q_out + (size_t)row * 1024))[threadIdx.x] = o;
        if (qbf) {
            bf16x4 ob = {(__bf16)o.x, (__bf16)o.y, (__bf16)o.z, (__bf16)o.w};
            ((bf16x4*)(qbf + (size_t)row * 1024))[threadIdx.x] = ob;
        }
    } else if (blk < 7168) {
        int w = blk - 4096;
        int sel = w >> 10, within = w & 1023;
        const float* in = (sel == 0) ? Wq : ((sel == 1) ? Wk : Wv);
        __bf16* out = (sel == 0) ? Wq_t : (Wkv_t + (size_t)(sel - 1) * 1048576);
        int k0 = (within >> 5) * 32, n0 = (within & 31) * 32;
        int tx = threadIdx.x & 31, ty = threadIdx.x >> 5;
#pragma unroll
        for (int i = 0; i < 4; i++)
            tile[ty + i * 8][tx] = in[(size_t)(k0 + ty + i * 8) * 1024 + n0 + tx];
        __syncthreads();
#pragma unroll
        for (int i = 0; i < 4; i++)
            out[(size_t)(n0 + ty + i * 8) * 1024 + k0 + tx] = (__bf16)tile[tx][ty + i * 8];
    } else if (mbits) {
        int row = blk - 7168;   // b*1024 + q
        const unsigned char* mrow = mask + (size_t)row * 1024;
        int wv = threadIdx.x >> 6, l = threadIdx.x & 63;
        unsigned long long* dst = (unsigned long long*)(mbits + (size_t)row * 32);
#pragma unroll
        for (int i = 0; i < 4; i++) {
            int key = i * 256 + wv * 64 + l;
            unsigned long long bal = __ballot(mrow[key] != 0);
            if (l == 0) dst[i * 4 + wv] = bal;
        }
    }
}

// ---- vtr: PV -> PVt[b,h,dh][5120]  (transpose only; 2560 blocks) ----
__global__ __launch_bounds__(256) void vtr_kernel(const __bf16* __restrict__ PV,
                                                  __bf16* __restrict__ PVt) {
    __shared__ __bf16 tile[64][72];
    int w = blockIdx.x;
    int bh = w / 80, kt = w % 80;
    int b = bh >> 4, h = bh & 15;
    int lidx = kt >> 4, i0 = (kt & 15) * 64;
    int kg0 = lidx * 2048 + b * 1024 + i0;
    int r = threadIdx.x >> 2, c16 = (threadIdx.x & 3) * 16;
    const __bf16* src = PV + (size_t)(kg0 + r) * 1024 + h * 64 + c16;
    *(bf16x8*)&tile[r][c16] = *(const bf16x8*)src;
    *(bf16x8*)&tile[r][c16 + 8] = *(const bf16x8*)(src + 8);
    __syncthreads();
    int dh = threadIdx.x >> 2, k0 = (threadIdx.x & 3) * 16;
    bf16x8 o0, o1;
#pragma unroll
    for (int j = 0; j < 8; j++) {
        o0[j] = tile[k0 + j][dh];
        o1[j] = tile[k0 + 8 + j][dh];
    }
    __bf16* dst = PVt + (size_t)(bh * 64 + dh) * 5120 + kt * 64 + k0;
    *(bf16x8*)dst = o0;
    *(bf16x8*)(dst + 8) = o1;
}

// ---------------- LayerNorm (LN2, small mode only) ----------------
__global__ __launch_bounds__(256) void ln_kernel(const float* __restrict__ x,
                                                 const float* __restrict__ g,
                                                 const float* __restrict__ bta,
                                                 __bf16* __restrict__ outb) {
    int row = blockIdx.x;
    const float4 v = ((const float4*)(x + (size_t)row * 1024))[threadIdx.x];
    float s = v.x + v.y + v.z + v.w;
    float s2 = v.x * v.x + v.y * v.y + v.z * v.z + v.w * v.w;
#pragma unroll
    for (int off = 1; off < 64; off <<= 1) {
        s += __shfl_xor(s, off);
        s2 += __shfl_xor(s2, off);
    }
    __shared__ float rs[4], rs2[4];
    int wv = threadIdx.x >> 6;
    if ((threadIdx.x & 63) == 0) { rs[wv] = s; rs2[wv] = s2; }
    __syncthreads();
    s = rs[0] + rs[1] + rs[2] + rs[3];
    s2 = rs2[0] + rs2[1] + rs2[2] + rs2[3];
    float mean = s * (1.0f / 1024.0f);
    float var = s2 * (1.0f / 1024.0f) - mean * mean;
    float rstd = rsqrtf(var + 1e-5f);
    float4 gg = ((const float4*)g)[threadIdx.x];
    float4 bb = ((const float4*)bta)[threadIdx.x];
    bf16x4 ob;
    ob[0] = (__bf16)((v.x - mean) * rstd * gg.x + bb.x);
    ob[1] = (__bf16)((v.y - mean) * rstd * gg.y + bb.y);
    ob[2] = (__bf16)((v.z - mean) * rstd * gg.z + bb.z);
    ob[3] = (__bf16)((v.w - mean) * rstd * gg.w + bb.w);
    ((bf16x4*)(outb + (size_t)row * 1024))[threadIdx.x] = ob;
}

// ---------------- fused Wo-combine (4 partials) + residual + LN2 ----------------
__global__ __launch_bounds__(256) void comb_ln2(const float* __restrict__ pc0,
                                                const float* __restrict__ pc1,
                                                const float* __restrict__ pc2,
                                                const float* __restrict__ pc3,
                                                const float* __restrict__ x,
                                                const float* __restrict__ g,
                                                const float* __restrict__ bta,
                                                float* __restrict__ x2,
                                                __bf16* __restrict__ fln) {
    int row = blockIdx.x;
    int idx = row * 256 + threadIdx.x;
    float4 a = ((const float4*)pc0)[idx];
    float4 b = ((const float4*)pc1)[idx];
    float4 c = ((const float4*)pc2)[idx];
    float4 d = ((const float4*)pc3)[idx];
    float4 r = ((const float4*)x)[idx];
    float4 v;
    v.x = (a.x + b.x) + (c.x + d.x) + r.x;
    v.y = (a.y + b.y) + (c.y + d.y) + r.y;
    v.z = (a.z + b.z) + (c.z + d.z) + r.z;
    v.w = (a.w + b.w) + (c.w + d.w) + r.w;
    ((float4*)x2)[idx] = v;
    float s = v.x + v.y + v.z + v.w;
    float s2 = v.x * v.x + v.y * v.y + v.z * v.z + v.w * v.w;
#pragma unroll
    for (int off = 1; off < 64; off <<= 1) {
        s += __shfl_xor(s, off);
        s2 += __shfl_xor(s2, off);
    }
    __shared__ float rs[4], rs2[4];
    int wv = threadIdx.x >> 6;
    if ((threadIdx.x & 63) == 0) { rs[wv] = s; rs2[wv] = s2; }
    __syncthreads();
    s = rs[0] + rs[1] + rs[2] + rs[3];
    s2 = rs2[0] + rs2[1] + rs2[2] + rs2[3];
    float mean = s * (1.0f / 1024.0f);
    float var = s2 * (1.0f / 1024.0f) - mean * mean;
    float rstd = rsqrtf(var + 1e-5f);
    float4 gg = ((const float4*)g)[threadIdx.x];
    float4 bb = ((const float4*)bta)[threadIdx.x];
    bf16x4 ob;
    ob[0] = (__bf16)((v.x - mean) * rstd * gg.x + bb.x);
    ob[1] = (__bf16)((v.y - mean) * rstd * gg.y + bb.y);
    ob[2] = (__bf16)((v.z - mean) * rstd * gg.z + bb.z);
    ob[3] = (__bf16)((v.w - mean) * rstd * gg.w + bb.w);
    ((bf16x4*)(fln + (size_t)row * 1024))[threadIdx.x] = ob;
}

// ---------------- transpose+convert (late weights, small mode) ----------------
__device__ __forceinline__ void tr_body(const float* __restrict__ in, __bf16* __restrict__ out,
                                        int K, int N, int k0, int n0) {
    __shared__ float tile[32][33];
    int tx = threadIdx.x & 31, ty = threadIdx.x >> 5;
#pragma unroll
    for (int i = 0; i < 4; i++)
        tile[ty + i * 8][tx] = in[(size_t)(k0 + ty + i * 8) * N + n0 + tx];
    __syncthreads();
#pragma unroll
    for (int i = 0; i < 4; i++)
        out[(size_t)(n0 + ty + i * 8) * K + k0 + tx] = (__bf16)tile[tx][ty + i * 8];
}

__global__ __launch_bounds__(256) void tr_late(const float* __restrict__ Wo,
                                               const float* __restrict__ W1,
                                               const float* __restrict__ W2,
                                               __bf16* __restrict__ Wo_t,
                                               __bf16* __restrict__ W1_t,
                                               __bf16* __restrict__ W2_t) {
    int w = blockIdx.x;
    const float* in;
    __bf16* out;
    int K, N, k0, n0;
    if (w < 1024) {
        in = Wo; out = Wo_t; K = 1024; N = 1024; n0 = (w & 31) * 32; k0 = (w >> 5) * 32;
    } else if (w < 5120) {
        int v = w - 1024;
        in = W1; out = W1_t; K = 1024; N = 4096; n0 = (v & 127) * 32; k0 = (v >> 7) * 32;
    } else {
        int v = w - 5120;
        in = W2; out = W2_t; K = 4096; N = 1024; n0 = (v & 31) * 32; k0 = (v >> 5) * 32;
    }
    tr_body(in, out, K, N, k0, n0);
}

// ---------------- GEMM core (BK=32) ----------------
template <int EPI, bool ABF16>
__device__ __forceinline__ void gemm_core(const void* __restrict__ Av,
                                          const __bf16* __restrict__ Bt,
                                          void* __restrict__ Cout,
                                          const float* __restrict__ bias,
                                          const float* __restrict__ res,
                                          int N, int lda, int ldb, int klen,
                                          float scale, int bm, int bn) {
    constexpr int LDA = ABF16 ? 32 : 40;
    __shared__ __bf16 As[128 * LDA];
    __shared__ __bf16 Bs[128 * 32];

    int t = threadIdx.x;
    int lane = t & 63, wave = t >> 6;
    int wm = (wave >> 1) * 64, wn = (wave & 1) * 64;
    int l16 = lane & 15, l4 = lane >> 4;

    f32x4 acc[4][4];
#pragma unroll
    for (int m = 0; m < 4; m++)
#pragma unroll
        for (int n = 0; n < 4; n++) acc[m][n] = (f32x4){0.f, 0.f, 0.f, 0.f};

    int srow = t >> 2;
    int scol = (t & 3) * 8;
    int ar = t >> 1, ak = (t & 1) * 16;
    const __bf16* Ab = (const __bf16*)Av;
    const float* Af = (const float*)Av;

    for (int k0 = 0; k0 < klen; k0 += 32) {
        gll16(Bt + (size_t)(bn + srow) * ldb + (k0 + scol), &Bs[wave * 512]);
        gll16(Bt + (size_t)(bn + 64 + srow) * ldb + (k0 + scol), &Bs[2048 + wave * 512]);
        if constexpr (ABF16) {
            gll16(Ab + (size_t)(bm + srow) * lda + (k0 + scol), &As[wave * 512]);
            gll16(Ab + (size_t)(bm + 64 + srow) * lda + (k0 + scol), &As[2048 + wave * 512]);
        } else {
            const float* ap = Af + (size_t)(bm + ar) * lda + k0 + ak;
            float4 f0 = ((const float4*)ap)[0];
            float4 f1 = ((const float4*)ap)[1];
            float4 f2 = ((const float4*)ap)[2];
            float4 f3 = ((const float4*)ap)[3];
            float ta[16] = {f0.x, f0.y, f0.z, f0.w, f1.x, f1.y, f1.z, f1.w,
                            f2.x, f2.y, f2.z, f2.w, f3.x, f3.y, f3.z, f3.w};
            bf16x8 v0, v1;
#pragma unroll
            for (int j = 0; j < 8; j++) { v0[j] = (__bf16)ta[j]; v1[j] = (__bf16)ta[j + 8]; }
            *(bf16x8*)&As[ar * 40 + ak] = v0;
            *(bf16x8*)&As[ar * 40 + ak + 8] = v1;
        }
        __syncthreads();

        bf16x8 af[4], bfr[4];
#pragma unroll
        for (int m = 0; m < 4; m++) af[m] = *(const bf16x8*)&As[(wm + m * 16 + l16) * LDA + l4 * 8];
#pragma unroll
        for (int n = 0; n < 4; n++) bfr[n] = *(const bf16x8*)&Bs[(wn + n * 16 + l16) * 32 + l4 * 8];
#pragma unroll
        for (int m = 0; m < 4; m++)
#pragma unroll
            for (int n = 0; n < 4; n++) acc[m][n] = MFMA16(af[m], bfr[n], acc[m][n]);
        __syncthreads();
    }

#pragma unroll
    for (int m = 0; m < 4; m++) {
#pragma unroll
        for (int r = 0; r < 4; r++) {
            int row = bm + wm + m * 16 + l4 * 4 + r;
#pragma unroll
            for (int n = 0; n < 4; n++) {
                int col = bn + wn + n * 16 + l16;
                float c = acc[m][n][r];
                size_t idx = (size_t)row * N + col;
                if (EPI == 0) {
                    ((__bf16*)Cout)[idx] = (__bf16)(c * scale);
                } else if (EPI == 1) {
                    ((float*)Cout)[idx] = c + res[idx];
                } else if (EPI == 2) {
                    ((__bf16*)Cout)[idx] = (__bf16)fmaxf(c + bias[col], 0.0f);
                } else if (EPI == 3) {
                    ((float*)Cout)[idx] = c + bias[col] + res[idx];
                } else {
                    ((float*)Cout)[idx] = c;
                }
            }
        }
    }
}

template <int EPI, bool ABF16>
__global__ __launch_bounds__(256) void gemm_bt(const void* __restrict__ Av,
                                               const __bf16* __restrict__ Bt,
                                               void* __restrict__ Cout,
                                               const float* __restrict__ bias,
                                               const float* __restrict__ res,
                                               int N, int K, float scale, int nbx) {
    int q = gridDim.x >> 3;
    int swz = (blockIdx.x & 7) * q + (blockIdx.x >> 3);
    int bn = (swz % nbx) * 128;
    int bm = (swz / nbx) * 128;
    gemm_core<EPI, ABF16>(Av, Bt, Cout, bias, res, N, K, K, K, scale, bm, bn);
}

// fused projections: KV (split PK/PV outputs) + Pq; V blocks read Wkv_t rows [1024,2048)
template <bool ABF16>
__global__ __launch_bounds__(256) void gemm_proj(const void* __restrict__ Akv,
                                                 const __bf16* __restrict__ Wkv_t,
                                                 __bf16* __restrict__ PK,
                                                 __bf16* __restrict__ PV,
                                                 const void* __restrict__ Aq,
                                                 const __bf16* __restrict__ Wq_t,
                                                 __bf16* __restrict__ Pq) {
    int q = gridDim.x >> 3;
    int swz = (blockIdx.x & 7) * q + (blockIdx.x >> 3);
    if (swz < 1280) {
        int bn = (swz & 15) * 128, bm = (swz >> 4) * 128;
        __bf16* C = (bn < 1024) ? PK : PV;
        int bnl = bn & 1023;
        const __bf16* Bt = Wkv_t + ((size_t)(bn & 1024) << 10);
        gemm_core<0, ABF16>(Akv, Bt, C, nullptr, nullptr, 1024, 1024, 1024, 1024, 1.0f, bm, bnl);
    } else {
        int p = swz - 1280;
        int bn = (p & 7) * 128, bm = (p >> 3) * 128;
        gemm_core<0, ABF16>(Aq, Wq_t, Pq, nullptr, nullptr, 1024, 1024, 1024, 1024,
                            0.125f * LOG2E, bm, bn);
    }
}

// W2 split-K4: 512 blocks, quarters of K=1024 each -> pc[quarter]
__global__ __launch_bounds__(256) void gemm_w2(const __bf16* __restrict__ h1,
                                               const __bf16* __restrict__ W2_t,
                                               float* __restrict__ pc0,
                                               float* __restrict__ pc1,
                                               float* __restrict__ pc2,
                                               float* __restrict__ pc3) {
    int q = gridDim.x >> 3;
    int swz = (blockIdx.x & 7) * q + (blockIdx.x >> 3);
    int quarter = swz >> 7;
    int p = swz & 127;
    int bn = (p & 7) * 128, bm = (p >> 3) * 128;
    int koff = quarter * 1024;
    float* pc = (quarter == 0) ? pc0 : (quarter == 1) ? pc1 : (quarter == 2) ? pc2 : pc3;
    gemm_core<4, true>(h1 + koff, W2_t + koff, pc, nullptr, nullptr,
                       1024, 4096, 4096, 1024, 1.0f, bm, bn);
}

// Wo split-K4: 512 blocks, quarters of K=256 each -> pc[quarter]
__global__ __launch_bounds__(256) void gemm_wo(const __bf16* __restrict__ ctx,
                                               const __bf16* __restrict__ Wo_t,
                                               float* __restrict__ pc0,
                                               float* __restrict__ pc1,
                                               float* __restrict__ pc2,
                                               float* __restrict__ pc3) {
    int q = gridDim.x >> 3;
    int swz = (blockIdx.x & 7) * q + (blockIdx.x >> 3);
    int quarter = swz >> 7;
    int p = swz & 127;
    int bn = (p & 7) * 128, bm = (p >> 3) * 128;
    int koff = quarter * 256;
    float* pc = (quarter == 0) ? pc0 : (quarter == 1) ? pc1 : (quarter == 2) ? pc2 : pc3;
    gemm_core<4, true>(ctx + koff, Wo_t + koff, pc, nullptr, nullptr,
                       1024, 1024, 1024, 256, 1.0f, bm, bn);
}

// combine 4 split-K partials: out = sum(pc) + res (+ bias)
__global__ __launch_bounds__(256) void comb_kernel(const float* __restrict__ pc0,
                                                   const float* __restrict__ pc1,
                                                   const float* __restrict__ pc2,
                                                   const float* __restrict__ pc3,
                                                   const float* __restrict__ bias,
                                                   const float* __restrict__ res,
                                                   float* __restrict__ out) {
    int i = blockIdx.x * 256 + threadIdx.x;
    float4 a = ((const float4*)pc0)[i];
    float4 b = ((const float4*)pc1)[i];
    float4 c = ((const float4*)pc2)[i];
    float4 d = ((const float4*)pc3)[i];
    float4 r = ((const float4*)res)[i];
    float4 o;
    o.x = (a.x + b.x) + (c.x + d.x) + r.x;
    o.y = (a.y + b.y) + (c.y + d.y) + r.y;
    o.z = (a.z + b.z) + (c.z + d.z) + r.z;
    o.w = (a.w + b.w) + (c.w + d.w) + r.w;
    if (bias) {
        float4 bb = ((const float4*)bias)[i & 255];
        o.x += bb.x; o.y += bb.y; o.z += bb.z; o.w += bb.w;
    }
    ((float4*)out)[i] = o;
}

// ---- attn softmax + in-register P redistribution (permlane32_swap) ----
__device__ __forceinline__ void softmax_p(const f32x16& s0, const f32x16& s1,
                                          unsigned int mka, unsigned int mkb,
                                          int hi, float& lsum, bf16x8* pf) {
    unsigned int ow[8][2];
#pragma unroll
    for (int g = 0; g < 4; g++) {
        bf16x4 p0, p1;
#pragma unroll
        for (int m = 0; m < 4; m++) {
            float e = exp2_fast(s0[g * 4 + m]);
            e = ((mka >> (g * 8 + hi * 4 + m)) & 1u) ? 0.0f : e;
            lsum += e;
            p0[m] = (__bf16)e;
            float e2 = exp2_fast(s1[g * 4 + m]);
            e2 = ((mkb >> (g * 8 + hi * 4 + m)) & 1u) ? 0.0f : e2;
            lsum += e2;
            p1[m] = (__bf16)e2;
        }
        ow[g][0] = ((unsigned int*)&p0)[0];
        ow[g][1] = ((unsigned int*)&p0)[1];
        ow[4 + g][0] = ((unsigned int*)&p1)[0];
        ow[4 + g][1] = ((unsigned int*)&p1)[1];
    }
#pragma unroll
    for (int ks = 0; ks < 4; ks++) {
        unsigned int a0 = ow[2 * ks][0], b0 = ow[2 * ks + 1][0];
        unsigned int a1 = ow[2 * ks][1], b1 = ow[2 * ks + 1][1];
        asm volatile("v_permlane32_swap_b32 %0, %1" : "+v"(a0), "+v"(b0));
        asm volatile("v_permlane32_swap_b32 %0, %1" : "+v"(a1), "+v"(b1));
        unsigned int* pp = (unsigned int*)&pf[ks];
        pp[0] = a0; pp[1] = a1; pp[2] = b0; pp[3] = b1;
    }
}

// ---- merged attention + transposes + f32 bank copy (big mode) ----------------------------
// blocks [0,1024): attention partials; [1024,10240): Wo/W1/W2 transpose;
// blocks [10240,12288): bank -> mem_out f32 copy (rides attn's idle HBM)
#define NCHP 20
__global__ __launch_bounds__(256, 2) void attn_tr(const __bf16* __restrict__ Pq,
                                                  const __bf16* __restrict__ PK,
                                                  const __bf16* __restrict__ PVt,
                                                  const unsigned int* __restrict__ mbits,
                                                  __bf16* __restrict__ pacc,
                                                  float* __restrict__ pl,
                                                  const float* __restrict__ Wo,
                                                  const float* __restrict__ W1,
                                                  const float* __restrict__ W2,
                                                  __bf16* __restrict__ Wo_t,
                                                  __bf16* __restrict__ W1_t,
                                                  __bf16* __restrict__ W2_t,
                                                  const float* __restrict__ bank,
                                                  float* __restrict__ mem_out) {
    __shared__ char smem[32768];
    int blk = blockIdx.x;
    if (blk >= 10240) {
        // ---- f32 bank copy filler ----
        int i = (blk - 10240) * 256 + threadIdx.x;
        const float4* i4 = (const float4*)bank;
        float4* o4 = (float4*)mem_out;
        for (; i < 2097152; i += 2048 * 256) o4[i] = i4[i];
        return;
    }
    if (blk >= 1024) {
        // ---- weight transpose (memory-bound filler) ----
        float (*tile)[33] = (float(*)[33])smem;
        int w = blk - 1024;
        const float* in;
        __bf16* out;
        int K, N, k0, n0;
        if (w < 1024) {
            in = Wo; out = Wo_t; K = 1024; N = 1024; n0 = (w & 31) * 32; k0 = (w >> 5) * 32;
        } else if (w < 5120) {
            int v = w - 1024;
            in = W1; out = W1_t; K = 1024; N = 4096; n0 = (v & 127) * 32; k0 = (v >> 7) * 32;
        } else {
            int v = w - 5120;
            in = W2; out = W2_t; K = 4096; N = 1024; n0 = (v & 31) * 32; k0 = (v >> 5) * 32;
        }
        int tx = threadIdx.x & 31, ty = threadIdx.x >> 5;
#pragma unroll
        for (int i = 0; i < 4; i++)
            tile[ty + i * 8][tx] = in[(size_t)(k0 + ty + i * 8) * N + n0 + tx];
        __syncthreads();
#pragma unroll
        for (int i = 0; i < 4; i++)
            out[(size_t)(n0 + ty + i * 8) * K + k0 + tx] = (__bf16)tile[tx][ty + i * 8];
        return;
    }

    // ---- attention partial (1 q-tile = 32 q per wave) ----
    __bf16 (*KB)[64][64] = (__bf16(*)[64][64])smem;            // [2][64][64] 16KB
    __bf16 (*VB)[64][64] = (__bf16(*)[64][64])(smem + 16384);  // [2][64][64] 16KB

    int bh = blk & 31;
    int qb = (blk >> 5) & 7;
    int rng = blk >> 8;
    int b = bh >> 4, h = bh & 15;
    int wave = threadIdx.x >> 6, lane = threadIdx.x & 63;
    int l32 = lane & 31, hi = lane >> 5;
    int q0 = qb * 128 + wave * 32;

    bf16x8 qf[4];
    {
        const __bf16* pqrow = Pq + (size_t)(b * 1024 + q0 + l32) * 1024 + h * 64 + hi * 8;
#pragma unroll
        for (int ds = 0; ds < 4; ds++) qf[ds] = *(const bf16x8*)(pqrow + ds * 16);
    }

    f32x16 acc0, acc1;
#pragma unroll
    for (int i = 0; i < 16; i++) { acc0[i] = 0.f; acc1[i] = 0.f; }
    float lsum = 0.0f;

    const unsigned int* mrow0 = mbits + (size_t)(b * 1024 + q0 + l32) * 32;

    int kgbase = rng * 1280;

    int idxA = wave * 8 + (lane >> 3);
    int idxB = (wave + 4) * 8 + (lane >> 3);
    int GA = (idxA ^ (idxA >> 3)) & 7;
    int GB = (idxB ^ (idxB >> 3)) & 7;
    int swA = (((lane & 7) ^ GA) << 4);
    int swB = (((lane & 7) ^ GB) << 4);
    size_t koffA = (size_t)idxA * 2048 + swA;
    size_t koffB = (size_t)idxB * 2048 + swB;
    size_t voffA = (size_t)idxA * 10240 + swA;
    size_t voffB = (size_t)idxB * 10240 + swB;

    int kmod = kgbase & 1023;
    const char* pkc = (const char*)PK + ((size_t)((kgbase >> 10) * 2048 + b * 1024 + kmod)) * 2048
                      + (size_t)h * 128;
    const char* pvc = (const char*)PVt + (size_t)(bh * 64) * 10240 + (size_t)kgbase * 2;

#define STAGE(BUF)                                            \
    do {                                                      \
        gll16(pkc + koffA, &KB[BUF][wave * 8][0]);            \
        gll16(pkc + koffB, &KB[BUF][(wave + 4) * 8][0]);      \
        gll16(pvc + voffA, &VB[BUF][wave * 8][0]);            \
        gll16(pvc + voffB, &VB[BUF][(wave + 4) * 8][0]);      \
    } while (0)
#define ADV()                                                          \
    do {                                                               \
        int st = (kmod + 64 >= 1024) ? (64 + 1024) : 64;               \
        kmod = (kmod + 64) & 1023;                                     \
        pkc += (size_t)st * 2048;                                      \
        pvc += 128;                                                    \
    } while (0)

    STAGE(0);
    ADV();
    int kd0 = (kgbase & 1023) >> 5;
    unsigned int mk0a = mrow0[kd0], mk0b = mrow0[kd0 + 1];

    int Gr0 = (l32 ^ (l32 >> 3)) & 7;
    int r1v = 32 + l32;
    int Gr1 = (r1v ^ (r1v >> 3)) & 7;

    for (int t = 0; t < NCHP; t++) {
        int buf = t & 1;
        __syncthreads();
        if (t + 1 < NCHP) {
            STAGE(buf ^ 1);
            ADV();
        }
        unsigned int nk0a = 0, nk0b = 0;
        if (t + 1 < NCHP) {
            int kdn = ((kgbase + (t + 1) * 64) & 1023) >> 5;
            nk0a = mrow0[kdn]; nk0b = mrow0[kdn + 1];
        }

        const __bf16* KsF = &KB[buf][0][0];
        const __bf16* VtF = &VB[buf][0][0];

        f32x16 s0, s1;
#pragma unroll
        for (int i = 0; i < 16; i++) { s0[i] = 0.f; s1[i] = 0.f; }
        __builtin_amdgcn_s_setprio(1);
#pragma unroll
        for (int ds = 0; ds < 4; ds++) {
            bf16x8 ka0 = *(const bf16x8*)&KsF[l32 * 64 + (((ds * 2 + hi) ^ Gr0) << 3)];
            bf16x8 ka1 = *(const bf16x8*)&KsF[r1v * 64 + (((ds * 2 + hi) ^ Gr1) << 3)];
            s0 = MFMA32(ka0, qf[ds], s0);
            s1 = MFMA32(ka1, qf[ds], s1);
        }
        __builtin_amdgcn_s_setprio(0);

        bf16x8 pf0[4];
        softmax_p(s0, s1, mk0a, mk0b, hi, lsum, pf0);

        mk0a = nk0a; mk0b = nk0b;

        __builtin_amdgcn_s_setprio(1);
#pragma unroll
        for (int ks = 0; ks < 4; ks++) {
            bf16x8 vf0 = *(const bf16x8*)&VtF[l32 * 64 + (((ks * 2 + hi) ^ Gr0) << 3)];
            bf16x8 vf1 = *(const bf16x8*)&VtF[r1v * 64 + (((ks * 2 + hi) ^ Gr1) << 3)];
            acc0 = MFMA32(vf0, pf0[ks], acc0);
            acc1 = MFMA32(vf1, pf0[ks], acc1);
        }
        __builtin_amdgcn_s_setprio(0);
    }
#undef STAGE
#undef ADV

    lsum += __shfl_xor(lsum, 32);

    size_t oblk = ((size_t)(bh * 8 + qb) * 4 + rng);
    __bf16* pa = pacc + oblk * 8192 + (size_t)(wave * 32 + l32) * 64;
#pragma unroll
    for (int g = 0; g < 4; g++) {
        bf16x4 o0, o1;
#pragma unroll
        for (int m = 0; m < 4; m++) {
            o0[m] = (__bf16)acc0[g * 4 + m];
            o1[m] = (__bf16)acc1[g * 4 + m];
        }
        *(bf16x4*)&pa[g * 8 + hi * 4] = o0;
        *(bf16x4*)&pa[32 + g * 8 + hi * 4] = o1;
    }
    if (hi == 0) pl[oblk * 128 + wave * 32 + l32] = lsum;
}

// combine the 4 key-range partials; grid (32 bh, 8 qb), 256 threads
__global__ __launch_bounds__(256) void attn_comb(const __bf16* __restrict__ pacc,
                                                 const float* __restrict__ pl,
                                                 __bf16* __restrict__ ctx) {
    int bh = blockIdx.x, qb = blockIdx.y;
    int b = bh >> 4, h = bh & 15;
    int q = threadIdx.x >> 1, dhalf = (threadIdx.x & 1) * 32;
    float acc[32];
#pragma unroll
    for (int j = 0; j < 32; j++) acc[j] = 0.0f;
    float l = 0.0f;
    size_t blk0 = ((size_t)(bh * 8 + qb)) * 4;
#pragma unroll
    for (int rng = 0; rng < 4; rng++) {
        size_t base = (blk0 + rng) * 8192 + (size_t)q * 64 + dhalf;
#pragma unroll
        for (int v = 0; v < 4; v++) {
            bf16x8 a = *(const bf16x8*)&pacc[base + v * 8];
#pragma unroll
            for (int j = 0; j < 8; j++) acc[v * 8 + j] += (float)a[j];
        }
        l += pl[(blk0 + rng) * 128 + q];
    }
    float inv = 1.0f / l;
    __bf16* crow = ctx + ((size_t)(b * 1024 + qb * 128 + q) << 10) + h * 64 + dhalf;
#pragma unroll
    for (int v = 0; v < 4; v++) {
        bf16x8 o;
#pragma unroll
        for (int j = 0; j < 8; j++) o[j] = (__bf16)(acc[v * 8 + j] * inv);
        *(bf16x8*)&crow[v * 8] = o;
    }
}

// ---------------- attention single-kernel fallback (small ws mode), split PK/PV ----------
#define KHALF 2560
#define CK 64
#define NCH 40
__global__ __launch_bounds__(512, 4) void attn_kernel(const __bf16* __restrict__ Pq,
                                                      const __bf16* __restrict__ PK,
                                                      const __bf16* __restrict__ PV,
                                                      const unsigned char* __restrict__ mask,
                                                      __bf16* __restrict__ ctx) {
    int bh = blockIdx.x;
    int b = bh >> 4, h = bh & 15;
    int wave = threadIdx.x >> 6, lane = threadIdx.x & 63;
    int grp = wave >> 2, wv = wave & 3;
    int l16 = lane & 15, l4 = lane >> 4;
    int q0 = blockIdx.y * 64 + wv * 16;

    __shared__ __bf16 Ks[2][64][72];
    __shared__ __bf16 Vt[2][64][72];
    __shared__ __bf16 Ps[8][16][72];

    const f32x4 fzero = {0.f, 0.f, 0.f, 0.f};

    bf16x8 qf[2];
    {
        const __bf16* pqrow = Pq + (size_t)(b * 1024 + q0 + l16) * 1024 + h * 64;
        qf[0] = *(const bf16x8*)(pqrow + l4 * 8);
        qf[1] = *(const bf16x8*)(pqrow + 32 + l4 * 8);
    }

    f32x4 accT[4];
#pragma unroll
    for (int n = 0; n < 4; n++) accT[n] = fzero;
    float lsum = 0.0f;

    const unsigned char* mrow_p = mask + (size_t)b * (1024u * 1024u) + (size_t)(q0 + l16) * 1024;

    int tl = threadIdx.x & 255;
    int skey = tl >> 2;
    int sd0 = (tl & 3) << 4;
    int kgbase = grp * KHALF;

    bf16x8 rk0, rk1, rv0, rv1;
    unsigned int mk[4], mkn[4];
    {
        int kg = kgbase + skey;
        int lidx = kg >> 10, i = kg & 1023;
        size_t off = (size_t)(lidx * 2048 + b * 1024 + i) * 1024 + h * 64 + sd0;
        rk0 = *(const bf16x8*)(PK + off);
        rk1 = *(const bf16x8*)(PK + off + 8);
        rv0 = *(const bf16x8*)(PV + off);
        rv1 = *(const bf16x8*)(PV + off + 8);
        int kloc = kgbase & 1023;
#pragma unroll
        for (int tile = 0; tile < 4; tile++)
            mk[tile] = *(const unsigned int*)(mrow_p + kloc + tile * 16 + l4 * 4);
    }

    for (int t = 0; t < NCH; t++) {
        *(bf16x8*)&Ks[grp][skey][sd0] = rk0;
        *(bf16x8*)&Ks[grp][skey][sd0 + 8] = rk1;
#pragma unroll
        for (int j = 0; j < 8; j++) {
            int row = sd0 + j;
            Vt[grp][row][skey ^ ((row >> 3) << 3)] = rv0[j];
            int row2 = sd0 + 8 + j;
            Vt[grp][row2][skey ^ ((row2 >> 3) << 3)] = rv1[j];
        }
        __syncthreads();

        if (t + 1 < NCH) {
            int kg = kgbase + (t + 1) * CK + skey;
            int lidx = kg >> 10, i = kg & 1023;
            size_t off = (size_t)(lidx * 2048 + b * 1024 + i) * 1024 + h * 64 + sd0;
            rk0 = *(const bf16x8*)(PK + off);
            rk1 = *(const bf16x8*)(PK + off + 8);
            rv0 = *(const bf16x8*)(PV + off);
            rv1 = *(const bf16x8*)(PV + off + 8);
            int kloc = (kgbase + (t + 1) * CK) & 1023;
#pragma unroll
            for (int tile = 0; tile < 4; tile++)
                mkn[tile] = *(const unsigned int*)(mrow_p + kloc + tile * 16 + l4 * 4);
        }

        f32x4 s[4];
        __builtin_amdgcn_s_setprio(1);
#pragma unroll
        for (int tile = 0; tile < 4; tile++) {
            bf16x8 ka = *(const bf16x8*)&Ks[grp][tile * 16 + l16][l4 * 8];
            bf16x8 kb = *(const bf16x8*)&Ks[grp][tile * 16 + l16][32 + l4 * 8];
            f32x4 sz = fzero;
            sz = MFMA16(ka, qf[0], sz);
            sz = MFMA16(kb, qf[1], sz);
            s[tile] = sz;
        }
        __builtin_amdgcn_s_setprio(0);

        float psum = 0.0f;
#pragma unroll
        for (int tile = 0; tile < 4; tile++) {
            bf16x4 pk_;
#pragma unroll
            for (int r = 0; r < 4; r++) {
                float e = exp2_fast(s[tile][r]);
                e = ((mk[tile] >> (r * 8)) & 255u) ? 0.0f : e;
                psum += e;
                pk_[r] = (__bf16)e;
            }
            *(bf16x4*)&Ps[wave][l16][tile * 16 + l4 * 4] = pk_;
        }
        lsum += psum;
#pragma unroll
        for (int tile = 0; tile < 4; tile++) mk[tile] = mkn[tile];

        __builtin_amdgcn_s_setprio(1);
#pragma unroll
        for (int kk = 0; kk < 2; kk++) {
            bf16x8 pf = *(const bf16x8*)&Ps[wave][l16][kk * 32 + l4 * 8];
#pragma unroll
            for (int n = 0; n < 4; n++) {
                int row = n * 16 + l16;
                int colblk = (kk * 32 + l4 * 8) ^ ((row >> 3) << 3);
                bf16x8 vf = *(const bf16x8*)&Vt[grp][row][colblk];
                accT[n] = MFMA16(vf, pf, accT[n]);
            }
        }
        __builtin_amdgcn_s_setprio(0);
        __syncthreads();
    }

    lsum += __shfl_xor(lsum, 16);
    lsum += __shfl_xor(lsum, 32);

    float* exAcc = (float*)&Ks[0][0][0];
    float* exL = (float*)&Vt[0][0][0];
    if (grp == 1) {
#pragma unroll
        for (int n = 0; n < 4; n++)
            *(f32x4*)&exAcc[(wv * 16 + l16) * 68 + n * 16 + l4 * 4] = accT[n];
        if (l4 == 0) exL[wv * 16 + l16] = lsum;
    }
    __syncthreads();
    if (grp == 0) {
        int qi = wv * 16 + l16;
        float inv = 1.0f / (lsum + exL[qi]);
        __bf16* crow = ctx + ((size_t)(b * 1024 + q0 + l16) << 10) + h * 64;
#pragma unroll
        for (int n = 0; n < 4; n++) {
            f32x4 a1 = *(const f32x4*)&exAcc[qi * 68 + n * 16 + l4 * 4];
            bf16x4 o;
#pragma unroll
            for (int r = 0; r < 4; r++) o[r] = (__bf16)((accT[n][r] + a1[r]) * inv);
            *(bf16x4*)&crow[n * 16 + l4 * 4] = o;
        }
    }
}

// ---------------- launcher ----------------
extern "C" void kernel_launch(void* const* d_in, const int* in_sizes, int n_in,
                              void* d_out, int out_size, void* d_ws, size_t ws_size,
                              hipStream_t stream) {
    const float* x = (const float*)d_in[0];
    const float* memory_bank = (const float*)d_in[1];
    const unsigned char* attn_mask = (const unsigned char*)d_in[2];
    const float* ln1_g = (const float*)d_in[3];
    const float* ln1_b = (const float*)d_in[4];
    const float* Wq = (const float*)d_in[5];
    const float* Wk = (const float*)d_in[6];
    const float* Wv = (const float*)d_in[7];
    const float* Wo = (const float*)d_in[8];
    const float* ln2_g = (const float*)d_in[9];
    const float* ln2_b = (const float*)d_in[10];
    const float* W1 = (const float*)d_in[11];
    const float* b1 = (const float*)d_in[12];
    const float* W2 = (const float*)d_in[13];
    const float* b2 = (const float*)d_in[14];

    float* out = (float*)d_out;
    float* mem_out = out + 2097152;
    float* q_out = mem_out + 4 * 2097152;

    char* ws = (char*)d_ws;
    bool big = ws_size >= (89ull << 20);

    __bf16* PK = (__bf16*)ws;                        // [0,20) both modes
    __bf16* PV = (__bf16*)(ws + (20ull << 20));      // [20,40) both modes
    __bf16 *Pq, *Wq_t, *Wkv_t, *ctx, *membf = nullptr, *qbf = nullptr;
    __bf16 *Wo_t, *W1_t, *W2_t;
    __bf16* PVt = nullptr;
    __bf16* pacc = nullptr;
    float* plv = nullptr;
    unsigned int* mbits = nullptr;
    if (big) {
        membf = (__bf16*)(ws + (40ull << 20));       // [40,60)
        qbf = membf + (size_t)8192 * 1024;           // [56,60)
        Wq_t = (__bf16*)(ws + (60ull << 20));        // [60,62)
        Wkv_t = (__bf16*)(ws + (62ull << 20));       // [62,66)
        Pq = (__bf16*)(ws + (66ull << 20));          // [66,70)
        mbits = (unsigned int*)(ws + (70ull << 20)); // [70,70.25)
        Wo_t = (__bf16*)(ws + (71ull << 20));        // [71,73)  outside PK (attn-concurrent)
        W1_t = (__bf16*)(ws + (73ull << 20));        // [73,81)
        W2_t = (__bf16*)(ws + (81ull << 20));        // [81,89)
        PVt = (__bf16*)(ws + (40ull << 20));         // [40,60) after proj (membf dead)
        pacc = (__bf16*)(ws + (20ull << 20));        // [20,36) during attn (PV dead post-vtr)
        plv = (float*)(ws + (36ull << 20));          // [36,36.5)
        ctx = (__bf16*)(ws + (60ull << 20));         // [60,64) after attn (Wq_t/Wkv_t dead)
    } else {
        Pq = (__bf16*)(ws + (40ull << 20));          // [40,44)
        Wq_t = (__bf16*)(ws + (44ull << 20));        // [44,46)
        Wkv_t = (__bf16*)(ws + (46ull << 20));       // [46,50)
        ctx = (__bf16*)(ws + (44ull << 20));         // [44,48) after proj
        Wo_t = (__bf16*)ws;                          // [0,2)
        W1_t = (__bf16*)(ws + (2ull << 20));         // [2,10)
        W2_t = (__bf16*)(ws + (10ull << 20));        // [10,18)
    }
    // phase B (both modes)
    float* x2 = (float*)(ws + (18ull << 20));     // [18,26)
    __bf16* fln = (__bf16*)(ws + (26ull << 20));  // [26,30)
    __bf16* h1 = (__bf16*)(ws + (30ull << 20));   // [30,46)
    // Wo split-K4 partials (big): dead regions at that point
    float* wo_pc0 = (float*)ws;                   // [0,8)
    float* wo_pc1 = (float*)(ws + (8ull << 20));  // [8,16)
    float* wo_pc2 = (float*)(ws + (30ull << 20)); // [30,38)
    float* wo_pc3 = (float*)(ws + (38ull << 20)); // [38,46)
    // W2 split-K4 partials (big): PVt/Wkv_t/Pq/mbits/Wo_t/W1_t dead by then
    float* pc0 = (float*)(ws + (46ull << 20));    // [46,54)
    float* pc1 = (float*)(ws + (54ull << 20));    // [54,62)
    float* pc2 = (float*)(ws + (62ull << 20));    // [62,70)
    float* pc3 = (float*)(ws + (70ull << 20));    // [70,78)

    // 1. prep: bank->membf (+f32 copy in small mode only), LN1 (+bf16), early transposes,
    //    mask bitpack (big). In big mode the f32 copy rides the attn_tr launch.
    prep_kernel<<<big ? 9216 : 7168, 256, 0, stream>>>(memory_bank, big ? nullptr : mem_out,
                                                       membf, x, ln1_g, ln1_b, q_out, qbf,
                                                       Wq, Wk, Wv, Wq_t, Wkv_t,
                                                       attn_mask, mbits);

    // 2. fused projections (split PK/PV)
    if (big)
        gemm_proj<true><<<1408, 256, 0, stream>>>(membf, Wkv_t, PK, PV, qbf, Wq_t, Pq);
    else
        gemm_proj<false><<<1408, 256, 0, stream>>>(mem_out, Wkv_t, PK, PV, q_out, Wq_t, Pq);

    // 3. attention (+ transposes + f32 bank copy merged into the same launch, big mode)
    if (big) {
        vtr_kernel<<<2560, 256, 0, stream>>>(PV, PVt);
        attn_tr<<<12288, 256, 0, stream>>>(Pq, PK, PVt, mbits, pacc, plv,
                                           Wo, W1, W2, Wo_t, W1_t, W2_t,
                                           memory_bank, mem_out);
        attn_comb<<<dim3(32, 8), 256, 0, stream>>>(pacc, plv, ctx);
    } else {
        attn_kernel<<<dim3(32, 16), 512, 0, stream>>>(Pq, PK, PV, attn_mask, ctx);
        tr_late<<<9216, 256, 0, stream>>>(Wo, W1, W2, Wo_t, W1_t, W2_t);
    }

    // 4. Wo + residual -> x2 (+ fused LN2 in big mode)
    if (big) {
        gemm_wo<<<512, 256, 0, stream>>>(ctx, Wo_t, wo_pc0, wo_pc1, wo_pc2, wo_pc3);
        comb_ln2<<<2048, 256, 0, stream>>>(wo_pc0, wo_pc1, wo_pc2, wo_pc3,
                                           x, ln2_g, ln2_b, x2, fln);
    } else {
        gemm_bt<1, true><<<128, 256, 0, stream>>>(ctx, Wo_t, x2, nullptr, x, 1024, 1024, 1.0f, 8);
        ln_kernel<<<2048, 256, 0, stream>>>(x2, ln2_g, ln2_b, fln);
    }
    // 5. FFN
    gemm_bt<2, true><<<512, 256, 0, stream>>>(fln, W1_t, h1, b1, nullptr, 4096, 1024, 1.0f, 32);
    if (big) {
        gemm_w2<<<512, 256, 0, stream>>>(h1, W2_t, pc0, pc1, pc2, pc3);
        comb_kernel<<<2048, 256, 0, stream>>>(pc0, pc1, pc2, pc3, b2, x2, out);
    } else {
        gemm_bt<3, true><<<128, 256, 0, stream>>>(h1, W2_t, out, b2, x2, 1024, 4096, 1.0f, 8);
    }
}

// Round 21
// 244.131 us; speedup vs baseline: 1.0205x; 1.0205x over previous
//
#include <hip/hip_runtime.h>
#include <hip/hip_bf16.h>

typedef __attribute__((ext_vector_type(8))) __bf16 bf16x8;
typedef __attribute__((ext_vector_type(4))) __bf16 bf16x4;
typedef __attribute__((ext_vector_type(4))) float f32x4;
typedef __attribute__((ext_vector_type(16))) float f32x16;

#define MFMA16(a, b, c) __builtin_amdgcn_mfma_f32_16x16x32_bf16((a), (b), (c), 0, 0, 0)
#define MFMA32(a, b, c) __builtin_amdgcn_mfma_f32_32x32x16_bf16((a), (b), (c), 0, 0, 0)
#define LOG2E 1.4426950408889634f

static __device__ __forceinline__ float exp2_fast(float x) {
    float r; asm("v_exp_f32 %0, %1" : "=v"(r) : "v"(x)); return r;
}

__device__ __forceinline__ void gll16(const void* g, void* l) {
    __builtin_amdgcn_global_load_lds((const __attribute__((address_space(1))) void*)g,
                                     (__attribute__((address_space(3))) void*)l,
                                     16, 0, 0);
}

// ---- prep: [0,2048) copy bank(+bf16); [2048,4096) LN1(+bf16); [4096,7168) weight transpose;
// ----       [7168,9216) mask bitpack (big mode only) ----
__global__ __launch_bounds__(256) void prep_kernel(const float* __restrict__ bank,
                                                   float* __restrict__ mem_out,
                                                   __bf16* __restrict__ membf,
                                                   const float* __restrict__ x,
                                                   const float* __restrict__ g,
                                                   const float* __restrict__ bta,
                                                   float* __restrict__ q_out,
                                                   __bf16* __restrict__ qbf,
                                                   const float* __restrict__ Wq,
                                                   const float* __restrict__ Wk,
                                                   const float* __restrict__ Wv,
                                                   __bf16* __restrict__ Wq_t,
                                                   __bf16* __restrict__ Wkv_t,
                                                   const unsigned char* __restrict__ mask,
                                                   unsigned int* __restrict__ mbits) {
    __shared__ float rs[4], rs2[4];
    __shared__ float tile[32][33];
    int blk = blockIdx.x;
    if (blk < 2048) {
        int i = blk * 256 + threadIdx.x;
        const float4* i4 = (const float4*)bank;
        float4* o4 = (float4*)mem_out;
        for (; i < 2097152; i += 2048 * 256) {
            float4 v = i4[i];
            o4[i] = v;
            if (membf) {
                bf16x4 ob = {(__bf16)v.x, (__bf16)v.y, (__bf16)v.z, (__bf16)v.w};
                ((bf16x4*)membf)[i] = ob;
            }
        }
    } else if (blk < 4096) {
        int row = blk - 2048;
        const float4 v = ((const float4*)(x + (size_t)row * 1024))[threadIdx.x];
        float s = v.x + v.y + v.z + v.w;
        float s2 = v.x * v.x + v.y * v.y + v.z * v.z + v.w * v.w;
#pragma unroll
        for (int off = 1; off < 64; off <<= 1) {
            s += __shfl_xor(s, off);
            s2 += __shfl_xor(s2, off);
        }
        int wv = threadIdx.x >> 6;
        if ((threadIdx.x & 63) == 0) { rs[wv] = s; rs2[wv] = s2; }
        __syncthreads();
        s = rs[0] + rs[1] + rs[2] + rs[3];
        s2 = rs2[0] + rs2[1] + rs2[2] + rs2[3];
        float mean = s * (1.0f / 1024.0f);
        float var = s2 * (1.0f / 1024.0f) - mean * mean;
        float rstd = rsqrtf(var + 1e-5f);
        float4 gg = ((const float4*)g)[threadIdx.x];
        float4 bb = ((const float4*)bta)[threadIdx.x];
        float4 o;
        o.x = (v.x - mean) * rstd * gg.x + bb.x;
        o.y = (v.y - mean) * rstd * gg.y + bb.y;
        o.z = (v.z - mean) * rstd * gg.z + bb.z;
        o.w = (v.w - mean) * rstd * gg.w + bb.w;
        ((float4*)(q_out + (size_t)row * 1024))[threadIdx.x] = o;
        if (qbf) {
            bf16x4 ob = {(__bf16)o.x, (__bf16)o.y, (__bf16)o.z, (__bf16)o.w};
            ((bf16x4*)(qbf + (size_t)row * 1024))[threadIdx.x] = ob;
        }
    } else if (blk < 7168) {
        int w = blk - 4096;
        int sel = w >> 10, within = w & 1023;
        const float* in = (sel == 0) ? Wq : ((sel == 1) ? Wk : Wv);
        __bf16* out = (sel == 0) ? Wq_t : (Wkv_t + (size_t)(sel - 1) * 1048576);
        int k0 = (within >> 5) * 32, n0 = (within & 31) * 32;
        int tx = threadIdx.x & 31, ty = threadIdx.x >> 5;
#pragma unroll
        for (int i = 0; i < 4; i++)
            tile[ty + i * 8][tx] = in[(size_t)(k0 + ty + i * 8) * 1024 + n0 + tx];
        __syncthreads();
#pragma unroll
        for (int i = 0; i < 4; i++)
            out[(size_t)(n0 + ty + i * 8) * 1024 + k0 + tx] = (__bf16)tile[tx][ty + i * 8];
    } else if (mbits) {
        int row = blk - 7168;   // b*1024 + q
        const unsigned char* mrow = mask + (size_t)row * 1024;
        int wv = threadIdx.x >> 6, l = threadIdx.x & 63;
        unsigned long long* dst = (unsigned long long*)(mbits + (size_t)row * 32);
#pragma unroll
        for (int i = 0; i < 4; i++) {
            int key = i * 256 + wv * 64 + l;
            unsigned long long bal = __ballot(mrow[key] != 0);
            if (l == 0) dst[i * 4 + wv] = bal;
        }
    }
}

// ---- vtr: PV -> PVt[b,h,dh][5120]  (transpose only; 2560 blocks) ----
__global__ __launch_bounds__(256) void vtr_kernel(const __bf16* __restrict__ PV,
                                                  __bf16* __restrict__ PVt) {
    __shared__ __bf16 tile[64][72];
    int w = blockIdx.x;
    int bh = w / 80, kt = w % 80;
    int b = bh >> 4, h = bh & 15;
    int lidx = kt >> 4, i0 = (kt & 15) * 64;
    int kg0 = lidx * 2048 + b * 1024 + i0;
    int r = threadIdx.x >> 2, c16 = (threadIdx.x & 3) * 16;
    const __bf16* src = PV + (size_t)(kg0 + r) * 1024 + h * 64 + c16;
    *(bf16x8*)&tile[r][c16] = *(const bf16x8*)src;
    *(bf16x8*)&tile[r][c16 + 8] = *(const bf16x8*)(src + 8);
    __syncthreads();
    int dh = threadIdx.x >> 2, k0 = (threadIdx.x & 3) * 16;
    bf16x8 o0, o1;
#pragma unroll
    for (int j = 0; j < 8; j++) {
        o0[j] = tile[k0 + j][dh];
        o1[j] = tile[k0 + 8 + j][dh];
    }
    __bf16* dst = PVt + (size_t)(bh * 64 + dh) * 5120 + kt * 64 + k0;
    *(bf16x8*)dst = o0;
    *(bf16x8*)(dst + 8) = o1;
}

// ---------------- LayerNorm (LN2, small mode only) ----------------
__global__ __launch_bounds__(256) void ln_kernel(const float* __restrict__ x,
                                                 const float* __restrict__ g,
                                                 const float* __restrict__ bta,
                                                 __bf16* __restrict__ outb) {
    int row = blockIdx.x;
    const float4 v = ((const float4*)(x + (size_t)row * 1024))[threadIdx.x];
    float s = v.x + v.y + v.z + v.w;
    float s2 = v.x * v.x + v.y * v.y + v.z * v.z + v.w * v.w;
#pragma unroll
    for (int off = 1; off < 64; off <<= 1) {
        s += __shfl_xor(s, off);
        s2 += __shfl_xor(s2, off);
    }
    __shared__ float rs[4], rs2[4];
    int wv = threadIdx.x >> 6;
    if ((threadIdx.x & 63) == 0) { rs[wv] = s; rs2[wv] = s2; }
    __syncthreads();
    s = rs[0] + rs[1] + rs[2] + rs[3];
    s2 = rs2[0] + rs2[1] + rs2[2] + rs2[3];
    float mean = s * (1.0f / 1024.0f);
    float var = s2 * (1.0f / 1024.0f) - mean * mean;
    float rstd = rsqrtf(var + 1e-5f);
    float4 gg = ((const float4*)g)[threadIdx.x];
    float4 bb = ((const float4*)bta)[threadIdx.x];
    bf16x4 ob;
    ob[0] = (__bf16)((v.x - mean) * rstd * gg.x + bb.x);
    ob[1] = (__bf16)((v.y - mean) * rstd * gg.y + bb.y);
    ob[2] = (__bf16)((v.z - mean) * rstd * gg.z + bb.z);
    ob[3] = (__bf16)((v.w - mean) * rstd * gg.w + bb.w);
    ((bf16x4*)(outb + (size_t)row * 1024))[threadIdx.x] = ob;
}

// ---------------- fused Wo-combine (4 partials) + residual + LN2 ----------------
__global__ __launch_bounds__(256) void comb_ln2(const float* __restrict__ pc0,
                                                const float* __restrict__ pc1,
                                                const float* __restrict__ pc2,
                                                const float* __restrict__ pc3,
                                                const float* __restrict__ x,
                                                const float* __restrict__ g,
                                                const float* __restrict__ bta,
                                                float* __restrict__ x2,
                                                __bf16* __restrict__ fln) {
    int row = blockIdx.x;
    int idx = row * 256 + threadIdx.x;
    float4 a = ((const float4*)pc0)[idx];
    float4 b = ((const float4*)pc1)[idx];
    float4 c = ((const float4*)pc2)[idx];
    float4 d = ((const float4*)pc3)[idx];
    float4 r = ((const float4*)x)[idx];
    float4 v;
    v.x = (a.x + b.x) + (c.x + d.x) + r.x;
    v.y = (a.y + b.y) + (c.y + d.y) + r.y;
    v.z = (a.z + b.z) + (c.z + d.z) + r.z;
    v.w = (a.w + b.w) + (c.w + d.w) + r.w;
    ((float4*)x2)[idx] = v;
    float s = v.x + v.y + v.z + v.w;
    float s2 = v.x * v.x + v.y * v.y + v.z * v.z + v.w * v.w;
#pragma unroll
    for (int off = 1; off < 64; off <<= 1) {
        s += __shfl_xor(s, off);
        s2 += __shfl_xor(s2, off);
    }
    __shared__ float rs[4], rs2[4];
    int wv = threadIdx.x >> 6;
    if ((threadIdx.x & 63) == 0) { rs[wv] = s; rs2[wv] = s2; }
    __syncthreads();
    s = rs[0] + rs[1] + rs[2] + rs[3];
    s2 = rs2[0] + rs2[1] + rs2[2] + rs2[3];
    float mean = s * (1.0f / 1024.0f);
    float var = s2 * (1.0f / 1024.0f) - mean * mean;
    float rstd = rsqrtf(var + 1e-5f);
    float4 gg = ((const float4*)g)[threadIdx.x];
    float4 bb = ((const float4*)bta)[threadIdx.x];
    bf16x4 ob;
    ob[0] = (__bf16)((v.x - mean) * rstd * gg.x + bb.x);
    ob[1] = (__bf16)((v.y - mean) * rstd * gg.y + bb.y);
    ob[2] = (__bf16)((v.z - mean) * rstd * gg.z + bb.z);
    ob[3] = (__bf16)((v.w - mean) * rstd * gg.w + bb.w);
    ((bf16x4*)(fln + (size_t)row * 1024))[threadIdx.x] = ob;
}

// ---------------- transpose+convert (late weights, small mode) ----------------
__device__ __forceinline__ void tr_body(const float* __restrict__ in, __bf16* __restrict__ out,
                                        int K, int N, int k0, int n0) {
    __shared__ float tile[32][33];
    int tx = threadIdx.x & 31, ty = threadIdx.x >> 5;
#pragma unroll
    for (int i = 0; i < 4; i++)
        tile[ty + i * 8][tx] = in[(size_t)(k0 + ty + i * 8) * N + n0 + tx];
    __syncthreads();
#pragma unroll
    for (int i = 0; i < 4; i++)
        out[(size_t)(n0 + ty + i * 8) * K + k0 + tx] = (__bf16)tile[tx][ty + i * 8];
}

__global__ __launch_bounds__(256) void tr_late(const float* __restrict__ Wo,
                                               const float* __restrict__ W1,
                                               const float* __restrict__ W2,
                                               __bf16* __restrict__ Wo_t,
                                               __bf16* __restrict__ W1_t,
                                               __bf16* __restrict__ W2_t) {
    int w = blockIdx.x;
    const float* in;
    __bf16* out;
    int K, N, k0, n0;
    if (w < 1024) {
        in = Wo; out = Wo_t; K = 1024; N = 1024; n0 = (w & 31) * 32; k0 = (w >> 5) * 32;
    } else if (w < 5120) {
        int v = w - 1024;
        in = W1; out = W1_t; K = 1024; N = 4096; n0 = (v & 127) * 32; k0 = (v >> 7) * 32;
    } else {
        int v = w - 5120;
        in = W2; out = W2_t; K = 4096; N = 1024; n0 = (v & 31) * 32; k0 = (v >> 5) * 32;
    }
    tr_body(in, out, K, N, k0, n0);
}

// ---------------- GEMM core (BK=32) ----------------
template <int EPI, bool ABF16>
__device__ __forceinline__ void gemm_core(const void* __restrict__ Av,
                                          const __bf16* __restrict__ Bt,
                                          void* __restrict__ Cout,
                                          const float* __restrict__ bias,
                                          const float* __restrict__ res,
                                          int N, int lda, int ldb, int klen,
                                          float scale, int bm, int bn) {
    constexpr int LDA = ABF16 ? 32 : 40;
    __shared__ __bf16 As[128 * LDA];
    __shared__ __bf16 Bs[128 * 32];

    int t = threadIdx.x;
    int lane = t & 63, wave = t >> 6;
    int wm = (wave >> 1) * 64, wn = (wave & 1) * 64;
    int l16 = lane & 15, l4 = lane >> 4;

    f32x4 acc[4][4];
#pragma unroll
    for (int m = 0; m < 4; m++)
#pragma unroll
        for (int n = 0; n < 4; n++) acc[m][n] = (f32x4){0.f, 0.f, 0.f, 0.f};

    int srow = t >> 2;
    int scol = (t & 3) * 8;
    int ar = t >> 1, ak = (t & 1) * 16;
    const __bf16* Ab = (const __bf16*)Av;
    const float* Af = (const float*)Av;

    for (int k0 = 0; k0 < klen; k0 += 32) {
        gll16(Bt + (size_t)(bn + srow) * ldb + (k0 + scol), &Bs[wave * 512]);
        gll16(Bt + (size_t)(bn + 64 + srow) * ldb + (k0 + scol), &Bs[2048 + wave * 512]);
        if constexpr (ABF16) {
            gll16(Ab + (size_t)(bm + srow) * lda + (k0 + scol), &As[wave * 512]);
            gll16(Ab + (size_t)(bm + 64 + srow) * lda + (k0 + scol), &As[2048 + wave * 512]);
        } else {
            const float* ap = Af + (size_t)(bm + ar) * lda + k0 + ak;
            float4 f0 = ((const float4*)ap)[0];
            float4 f1 = ((const float4*)ap)[1];
            float4 f2 = ((const float4*)ap)[2];
            float4 f3 = ((const float4*)ap)[3];
            float ta[16] = {f0.x, f0.y, f0.z, f0.w, f1.x, f1.y, f1.z, f1.w,
                            f2.x, f2.y, f2.z, f2.w, f3.x, f3.y, f3.z, f3.w};
            bf16x8 v0, v1;
#pragma unroll
            for (int j = 0; j < 8; j++) { v0[j] = (__bf16)ta[j]; v1[j] = (__bf16)ta[j + 8]; }
            *(bf16x8*)&As[ar * 40 + ak] = v0;
            *(bf16x8*)&As[ar * 40 + ak + 8] = v1;
        }
        __syncthreads();

        bf16x8 af[4], bfr[4];
#pragma unroll
        for (int m = 0; m < 4; m++) af[m] = *(const bf16x8*)&As[(wm + m * 16 + l16) * LDA + l4 * 8];
#pragma unroll
        for (int n = 0; n < 4; n++) bfr[n] = *(const bf16x8*)&Bs[(wn + n * 16 + l16) * 32 + l4 * 8];
#pragma unroll
        for (int m = 0; m < 4; m++)
#pragma unroll
            for (int n = 0; n < 4; n++) acc[m][n] = MFMA16(af[m], bfr[n], acc[m][n]);
        __syncthreads();
    }

#pragma unroll
    for (int m = 0; m < 4; m++) {
#pragma unroll
        for (int r = 0; r < 4; r++) {
            int row = bm + wm + m * 16 + l4 * 4 + r;
#pragma unroll
            for (int n = 0; n < 4; n++) {
                int col = bn + wn + n * 16 + l16;
                float c = acc[m][n][r];
                size_t idx = (size_t)row * N + col;
                if (EPI == 0) {
                    ((__bf16*)Cout)[idx] = (__bf16)(c * scale);
                } else if (EPI == 1) {
                    ((float*)Cout)[idx] = c + res[idx];
                } else if (EPI == 2) {
                    ((__bf16*)Cout)[idx] = (__bf16)fmaxf(c + bias[col], 0.0f);
                } else if (EPI == 3) {
                    ((float*)Cout)[idx] = c + bias[col] + res[idx];
                } else {
                    ((float*)Cout)[idx] = c;
                }
            }
        }
    }
}

template <int EPI, bool ABF16>
__global__ __launch_bounds__(256) void gemm_bt(const void* __restrict__ Av,
                                               const __bf16* __restrict__ Bt,
                                               void* __restrict__ Cout,
                                               const float* __restrict__ bias,
                                               const float* __restrict__ res,
                                               int N, int K, float scale, int nbx) {
    int q = gridDim.x >> 3;
    int swz = (blockIdx.x & 7) * q + (blockIdx.x >> 3);
    int bn = (swz % nbx) * 128;
    int bm = (swz / nbx) * 128;
    gemm_core<EPI, ABF16>(Av, Bt, Cout, bias, res, N, K, K, K, scale, bm, bn);
}

// fused projections: KV (split PK/PV outputs) + Pq; V blocks read Wkv_t rows [1024,2048)
template <bool ABF16>
__global__ __launch_bounds__(256) void gemm_proj(const void* __restrict__ Akv,
                                                 const __bf16* __restrict__ Wkv_t,
                                                 __bf16* __restrict__ PK,
                                                 __bf16* __restrict__ PV,
                                                 const void* __restrict__ Aq,
                                                 const __bf16* __restrict__ Wq_t,
                                                 __bf16* __restrict__ Pq) {
    int q = gridDim.x >> 3;
    int swz = (blockIdx.x & 7) * q + (blockIdx.x >> 3);
    if (swz < 1280) {
        int bn = (swz & 15) * 128, bm = (swz >> 4) * 128;
        __bf16* C = (bn < 1024) ? PK : PV;
        int bnl = bn & 1023;
        const __bf16* Bt = Wkv_t + ((size_t)(bn & 1024) << 10);
        gemm_core<0, ABF16>(Akv, Bt, C, nullptr, nullptr, 1024, 1024, 1024, 1024, 1.0f, bm, bnl);
    } else {
        int p = swz - 1280;
        int bn = (p & 7) * 128, bm = (p >> 3) * 128;
        gemm_core<0, ABF16>(Aq, Wq_t, Pq, nullptr, nullptr, 1024, 1024, 1024, 1024,
                            0.125f * LOG2E, bm, bn);
    }
}

// W2 split-K4: 512 blocks, quarters of K=1024 each -> pc[quarter]
__global__ __launch_bounds__(256) void gemm_w2(const __bf16* __restrict__ h1,
                                               const __bf16* __restrict__ W2_t,
                                               float* __restrict__ pc0,
                                               float* __restrict__ pc1,
                                               float* __restrict__ pc2,
                                               float* __restrict__ pc3) {
    int q = gridDim.x >> 3;
    int swz = (blockIdx.x & 7) * q + (blockIdx.x >> 3);
    int quarter = swz >> 7;
    int p = swz & 127;
    int bn = (p & 7) * 128, bm = (p >> 3) * 128;
    int koff = quarter * 1024;
    float* pc = (quarter == 0) ? pc0 : (quarter == 1) ? pc1 : (quarter == 2) ? pc2 : pc3;
    gemm_core<4, true>(h1 + koff, W2_t + koff, pc, nullptr, nullptr,
                       1024, 4096, 4096, 1024, 1.0f, bm, bn);
}

// Wo split-K4: 512 blocks, quarters of K=256 each -> pc[quarter]
__global__ __launch_bounds__(256) void gemm_wo(const __bf16* __restrict__ ctx,
                                               const __bf16* __restrict__ Wo_t,
                                               float* __restrict__ pc0,
                                               float* __restrict__ pc1,
                                               float* __restrict__ pc2,
                                               float* __restrict__ pc3) {
    int q = gridDim.x >> 3;
    int swz = (blockIdx.x & 7) * q + (blockIdx.x >> 3);
    int quarter = swz >> 7;
    int p = swz & 127;
    int bn = (p & 7) * 128, bm = (p >> 3) * 128;
    int koff = quarter * 256;
    float* pc = (quarter == 0) ? pc0 : (quarter == 1) ? pc1 : (quarter == 2) ? pc2 : pc3;
    gemm_core<4, true>(ctx + koff, Wo_t + koff, pc, nullptr, nullptr,
                       1024, 1024, 1024, 256, 1.0f, bm, bn);
}

// combine 4 split-K partials: out = sum(pc) + res (+ bias)
__global__ __launch_bounds__(256) void comb_kernel(const float* __restrict__ pc0,
                                                   const float* __restrict__ pc1,
                                                   const float* __restrict__ pc2,
                                                   const float* __restrict__ pc3,
                                                   const float* __restrict__ bias,
                                                   const float* __restrict__ res,
                                                   float* __restrict__ out) {
    int i = blockIdx.x * 256 + threadIdx.x;
    float4 a = ((const float4*)pc0)[i];
    float4 b = ((const float4*)pc1)[i];
    float4 c = ((const float4*)pc2)[i];
    float4 d = ((const float4*)pc3)[i];
    float4 r = ((const float4*)res)[i];
    float4 o;
    o.x = (a.x + b.x) + (c.x + d.x) + r.x;
    o.y = (a.y + b.y) + (c.y + d.y) + r.y;
    o.z = (a.z + b.z) + (c.z + d.z) + r.z;
    o.w = (a.w + b.w) + (c.w + d.w) + r.w;
    if (bias) {
        float4 bb = ((const float4*)bias)[i & 255];
        o.x += bb.x; o.y += bb.y; o.z += bb.z; o.w += bb.w;
    }
    ((float4*)out)[i] = o;
}

// ---- attn softmax + in-register P redistribution (permlane32_swap) ----
__device__ __forceinline__ void softmax_p(const f32x16& s0, const f32x16& s1,
                                          unsigned int mka, unsigned int mkb,
                                          int hi, float& lsum, bf16x8* pf) {
    unsigned int ow[8][2];
#pragma unroll
    for (int g = 0; g < 4; g++) {
        bf16x4 p0, p1;
#pragma unroll
        for (int m = 0; m < 4; m++) {
            float e = exp2_fast(s0[g * 4 + m]);
            e = ((mka >> (g * 8 + hi * 4 + m)) & 1u) ? 0.0f : e;
            lsum += e;
            p0[m] = (__bf16)e;
            float e2 = exp2_fast(s1[g * 4 + m]);
            e2 = ((mkb >> (g * 8 + hi * 4 + m)) & 1u) ? 0.0f : e2;
            lsum += e2;
            p1[m] = (__bf16)e2;
        }
        ow[g][0] = ((unsigned int*)&p0)[0];
        ow[g][1] = ((unsigned int*)&p0)[1];
        ow[4 + g][0] = ((unsigned int*)&p1)[0];
        ow[4 + g][1] = ((unsigned int*)&p1)[1];
    }
#pragma unroll
    for (int ks = 0; ks < 4; ks++) {
        unsigned int a0 = ow[2 * ks][0], b0 = ow[2 * ks + 1][0];
        unsigned int a1 = ow[2 * ks][1], b1 = ow[2 * ks + 1][1];
        asm volatile("v_permlane32_swap_b32 %0, %1" : "+v"(a0), "+v"(b0));
        asm volatile("v_permlane32_swap_b32 %0, %1" : "+v"(a1), "+v"(b1));
        unsigned int* pp = (unsigned int*)&pf[ks];
        pp[0] = a0; pp[1] = a1; pp[2] = b0; pp[3] = b1;
    }
}

// ---- merged attention + late-weight-transpose kernel (big mode) --------------------------
// blocks [0,1024): attention partials, 1 q-tile/wave (32 q): bh=blk&31, qb=(blk>>5)&7, rng=blk>>8
// blocks [1024,10240): Wo/W1/W2 transpose (fills idle CU slots during attention)
#define NCHP 20
__global__ __launch_bounds__(256, 2) void attn_tr(const __bf16* __restrict__ Pq,
                                                  const __bf16* __restrict__ PK,
                                                  const __bf16* __restrict__ PVt,
                                                  const unsigned int* __restrict__ mbits,
                                                  __bf16* __restrict__ pacc,
                                                  float* __restrict__ pl,
                                                  const float* __restrict__ Wo,
                                                  const float* __restrict__ W1,
                                                  const float* __restrict__ W2,
                                                  __bf16* __restrict__ Wo_t,
                                                  __bf16* __restrict__ W1_t,
                                                  __bf16* __restrict__ W2_t) {
    __shared__ char smem[32768];
    int blk = blockIdx.x;
    if (blk >= 1024) {
        // ---- weight transpose (memory-bound filler) ----
        float (*tile)[33] = (float(*)[33])smem;
        int w = blk - 1024;
        const float* in;
        __bf16* out;
        int K, N, k0, n0;
        if (w < 1024) {
            in = Wo; out = Wo_t; K = 1024; N = 1024; n0 = (w & 31) * 32; k0 = (w >> 5) * 32;
        } else if (w < 5120) {
            int v = w - 1024;
            in = W1; out = W1_t; K = 1024; N = 4096; n0 = (v & 127) * 32; k0 = (v >> 7) * 32;
        } else {
            int v = w - 5120;
            in = W2; out = W2_t; K = 4096; N = 1024; n0 = (v & 31) * 32; k0 = (v >> 5) * 32;
        }
        int tx = threadIdx.x & 31, ty = threadIdx.x >> 5;
#pragma unroll
        for (int i = 0; i < 4; i++)
            tile[ty + i * 8][tx] = in[(size_t)(k0 + ty + i * 8) * N + n0 + tx];
        __syncthreads();
#pragma unroll
        for (int i = 0; i < 4; i++)
            out[(size_t)(n0 + ty + i * 8) * K + k0 + tx] = (__bf16)tile[tx][ty + i * 8];
        return;
    }

    // ---- attention partial (1 q-tile = 32 q per wave) ----
    __bf16 (*KB)[64][64] = (__bf16(*)[64][64])smem;            // [2][64][64] 16KB
    __bf16 (*VB)[64][64] = (__bf16(*)[64][64])(smem + 16384);  // [2][64][64] 16KB

    int bh = blk & 31;
    int qb = (blk >> 5) & 7;
    int rng = blk >> 8;
    int b = bh >> 4, h = bh & 15;
    int wave = threadIdx.x >> 6, lane = threadIdx.x & 63;
    int l32 = lane & 31, hi = lane >> 5;
    int q0 = qb * 128 + wave * 32;

    bf16x8 qf[4];
    {
        const __bf16* pqrow = Pq + (size_t)(b * 1024 + q0 + l32) * 1024 + h * 64 + hi * 8;
#pragma unroll
        for (int ds = 0; ds < 4; ds++) qf[ds] = *(const bf16x8*)(pqrow + ds * 16);
    }

    f32x16 acc0, acc1;
#pragma unroll
    for (int i = 0; i < 16; i++) { acc0[i] = 0.f; acc1[i] = 0.f; }
    float lsum = 0.0f;

    const unsigned int* mrow0 = mbits + (size_t)(b * 1024 + q0 + l32) * 32;

    int kgbase = rng * 1280;

    int idxA = wave * 8 + (lane >> 3);
    int idxB = (wave + 4) * 8 + (lane >> 3);
    int GA = (idxA ^ (idxA >> 3)) & 7;
    int GB = (idxB ^ (idxB >> 3)) & 7;
    int swA = (((lane & 7) ^ GA) << 4);
    int swB = (((lane & 7) ^ GB) << 4);
    size_t koffA = (size_t)idxA * 2048 + swA;
    size_t koffB = (size_t)idxB * 2048 + swB;
    size_t voffA = (size_t)idxA * 10240 + swA;
    size_t voffB = (size_t)idxB * 10240 + swB;

    int kmod = kgbase & 1023;
    const char* pkc = (const char*)PK + ((size_t)((kgbase >> 10) * 2048 + b * 1024 + kmod)) * 2048
                      + (size_t)h * 128;
    const char* pvc = (const char*)PVt + (size_t)(bh * 64) * 10240 + (size_t)kgbase * 2;

#define STAGE(BUF)                                            \
    do {                                                      \
        gll16(pkc + koffA, &KB[BUF][wave * 8][0]);            \
        gll16(pkc + koffB, &KB[BUF][(wave + 4) * 8][0]);      \
        gll16(pvc + voffA, &VB[BUF][wave * 8][0]);            \
        gll16(pvc + voffB, &VB[BUF][(wave + 4) * 8][0]);      \
    } while (0)
#define ADV()                                                          \
    do {                                                               \
        int st = (kmod + 64 >= 1024) ? (64 + 1024) : 64;               \
        kmod = (kmod + 64) & 1023;                                     \
        pkc += (size_t)st * 2048;                                      \
        pvc += 128;                                                    \
    } while (0)

    STAGE(0);
    ADV();
    int kd0 = (kgbase & 1023) >> 5;
    unsigned int mk0a = mrow0[kd0], mk0b = mrow0[kd0 + 1];

    int Gr0 = (l32 ^ (l32 >> 3)) & 7;
    int r1v = 32 + l32;
    int Gr1 = (r1v ^ (r1v >> 3)) & 7;

    for (int t = 0; t < NCHP; t++) {
        int buf = t & 1;
        __syncthreads();
        if (t + 1 < NCHP) {
            STAGE(buf ^ 1);
            ADV();
        }
        unsigned int nk0a = 0, nk0b = 0;
        if (t + 1 < NCHP) {
            int kdn = ((kgbase + (t + 1) * 64) & 1023) >> 5;
            nk0a = mrow0[kdn]; nk0b = mrow0[kdn + 1];
        }

        const __bf16* KsF = &KB[buf][0][0];
        const __bf16* VtF = &VB[buf][0][0];

        f32x16 s0, s1;
#pragma unroll
        for (int i = 0; i < 16; i++) { s0[i] = 0.f; s1[i] = 0.f; }
        __builtin_amdgcn_s_setprio(1);
#pragma unroll
        for (int ds = 0; ds < 4; ds++) {
            bf16x8 ka0 = *(const bf16x8*)&KsF[l32 * 64 + (((ds * 2 + hi) ^ Gr0) << 3)];
            bf16x8 ka1 = *(const bf16x8*)&KsF[r1v * 64 + (((ds * 2 + hi) ^ Gr1) << 3)];
            s0 = MFMA32(ka0, qf[ds], s0);
            s1 = MFMA32(ka1, qf[ds], s1);
        }
        __builtin_amdgcn_s_setprio(0);

        bf16x8 pf0[4];
        softmax_p(s0, s1, mk0a, mk0b, hi, lsum, pf0);

        mk0a = nk0a; mk0b = nk0b;

        __builtin_amdgcn_s_setprio(1);
#pragma unroll
        for (int ks = 0; ks < 4; ks++) {
            bf16x8 vf0 = *(const bf16x8*)&VtF[l32 * 64 + (((ks * 2 + hi) ^ Gr0) << 3)];
            bf16x8 vf1 = *(const bf16x8*)&VtF[r1v * 64 + (((ks * 2 + hi) ^ Gr1) << 3)];
            acc0 = MFMA32(vf0, pf0[ks], acc0);
            acc1 = MFMA32(vf1, pf0[ks], acc1);
        }
        __builtin_amdgcn_s_setprio(0);
    }
#undef STAGE
#undef ADV

    lsum += __shfl_xor(lsum, 32);

    size_t oblk = ((size_t)(bh * 8 + qb) * 4 + rng);
    __bf16* pa = pacc + oblk * 8192 + (size_t)(wave * 32 + l32) * 64;
#pragma unroll
    for (int g = 0; g < 4; g++) {
        bf16x4 o0, o1;
#pragma unroll
        for (int m = 0; m < 4; m++) {
            o0[m] = (__bf16)acc0[g * 4 + m];
            o1[m] = (__bf16)acc1[g * 4 + m];
        }
        *(bf16x4*)&pa[g * 8 + hi * 4] = o0;
        *(bf16x4*)&pa[32 + g * 8 + hi * 4] = o1;
    }
    if (hi == 0) pl[oblk * 128 + wave * 32 + l32] = lsum;
}

// combine the 4 key-range partials; grid (32 bh, 8 qb), 256 threads
__global__ __launch_bounds__(256) void attn_comb(const __bf16* __restrict__ pacc,
                                                 const float* __restrict__ pl,
                                                 __bf16* __restrict__ ctx) {
    int bh = blockIdx.x, qb = blockIdx.y;
    int b = bh >> 4, h = bh & 15;
    int q = threadIdx.x >> 1, dhalf = (threadIdx.x & 1) * 32;
    float acc[32];
#pragma unroll
    for (int j = 0; j < 32; j++) acc[j] = 0.0f;
    float l = 0.0f;
    size_t blk0 = ((size_t)(bh * 8 + qb)) * 4;
#pragma unroll
    for (int rng = 0; rng < 4; rng++) {
        size_t base = (blk0 + rng) * 8192 + (size_t)q * 64 + dhalf;
#pragma unroll
        for (int v = 0; v < 4; v++) {
            bf16x8 a = *(const bf16x8*)&pacc[base + v * 8];
#pragma unroll
            for (int j = 0; j < 8; j++) acc[v * 8 + j] += (float)a[j];
        }
        l += pl[(blk0 + rng) * 128 + q];
    }
    float inv = 1.0f / l;
    __bf16* crow = ctx + ((size_t)(b * 1024 + qb * 128 + q) << 10) + h * 64 + dhalf;
#pragma unroll
    for (int v = 0; v < 4; v++) {
        bf16x8 o;
#pragma unroll
        for (int j = 0; j < 8; j++) o[j] = (__bf16)(acc[v * 8 + j] * inv);
        *(bf16x8*)&crow[v * 8] = o;
    }
}

// ---------------- attention single-kernel fallback (small ws mode), split PK/PV ----------
#define KHALF 2560
#define CK 64
#define NCH 40
__global__ __launch_bounds__(512, 4) void attn_kernel(const __bf16* __restrict__ Pq,
                                                      const __bf16* __restrict__ PK,
                                                      const __bf16* __restrict__ PV,
                                                      const unsigned char* __restrict__ mask,
                                                      __bf16* __restrict__ ctx) {
    int bh = blockIdx.x;
    int b = bh >> 4, h = bh & 15;
    int wave = threadIdx.x >> 6, lane = threadIdx.x & 63;
    int grp = wave >> 2, wv = wave & 3;
    int l16 = lane & 15, l4 = lane >> 4;
    int q0 = blockIdx.y * 64 + wv * 16;

    __shared__ __bf16 Ks[2][64][72];
    __shared__ __bf16 Vt[2][64][72];
    __shared__ __bf16 Ps[8][16][72];

    const f32x4 fzero = {0.f, 0.f, 0.f, 0.f};

    bf16x8 qf[2];
    {
        const __bf16* pqrow = Pq + (size_t)(b * 1024 + q0 + l16) * 1024 + h * 64;
        qf[0] = *(const bf16x8*)(pqrow + l4 * 8);
        qf[1] = *(const bf16x8*)(pqrow + 32 + l4 * 8);
    }

    f32x4 accT[4];
#pragma unroll
    for (int n = 0; n < 4; n++) accT[n] = fzero;
    float lsum = 0.0f;

    const unsigned char* mrow_p = mask + (size_t)b * (1024u * 1024u) + (size_t)(q0 + l16) * 1024;

    int tl = threadIdx.x & 255;
    int skey = tl >> 2;
    int sd0 = (tl & 3) << 4;
    int kgbase = grp * KHALF;

    bf16x8 rk0, rk1, rv0, rv1;
    unsigned int mk[4], mkn[4];
    {
        int kg = kgbase + skey;
        int lidx = kg >> 10, i = kg & 1023;
        size_t off = (size_t)(lidx * 2048 + b * 1024 + i) * 1024 + h * 64 + sd0;
        rk0 = *(const bf16x8*)(PK + off);
        rk1 = *(const bf16x8*)(PK + off + 8);
        rv0 = *(const bf16x8*)(PV + off);
        rv1 = *(const bf16x8*)(PV + off + 8);
        int kloc = kgbase & 1023;
#pragma unroll
        for (int tile = 0; tile < 4; tile++)
            mk[tile] = *(const unsigned int*)(mrow_p + kloc + tile * 16 + l4 * 4);
    }

    for (int t = 0; t < NCH; t++) {
        *(bf16x8*)&Ks[grp][skey][sd0] = rk0;
        *(bf16x8*)&Ks[grp][skey][sd0 + 8] = rk1;
#pragma unroll
        for (int j = 0; j < 8; j++) {
            int row = sd0 + j;
            Vt[grp][row][skey ^ ((row >> 3) << 3)] = rv0[j];
            int row2 = sd0 + 8 + j;
            Vt[grp][row2][skey ^ ((row2 >> 3) << 3)] = rv1[j];
        }
        __syncthreads();

        if (t + 1 < NCH) {
            int kg = kgbase + (t + 1) * CK + skey;
            int lidx = kg >> 10, i = kg & 1023;
            size_t off = (size_t)(lidx * 2048 + b * 1024 + i) * 1024 + h * 64 + sd0;
            rk0 = *(const bf16x8*)(PK + off);
            rk1 = *(const bf16x8*)(PK + off + 8);
            rv0 = *(const bf16x8*)(PV + off);
            rv1 = *(const bf16x8*)(PV + off + 8);
            int kloc = (kgbase + (t + 1) * CK) & 1023;
#pragma unroll
            for (int tile = 0; tile < 4; tile++)
                mkn[tile] = *(const unsigned int*)(mrow_p + kloc + tile * 16 + l4 * 4);
        }

        f32x4 s[4];
        __builtin_amdgcn_s_setprio(1);
#pragma unroll
        for (int tile = 0; tile < 4; tile++) {
            bf16x8 ka = *(const bf16x8*)&Ks[grp][tile * 16 + l16][l4 * 8];
            bf16x8 kb = *(const bf16x8*)&Ks[grp][tile * 16 + l16][32 + l4 * 8];
            f32x4 sz = fzero;
            sz = MFMA16(ka, qf[0], sz);
            sz = MFMA16(kb, qf[1], sz);
            s[tile] = sz;
        }
        __builtin_amdgcn_s_setprio(0);

        float psum = 0.0f;
#pragma unroll
        for (int tile = 0; tile < 4; tile++) {
            bf16x4 pk_;
#pragma unroll
            for (int r = 0; r < 4; r++) {
                float e = exp2_fast(s[tile][r]);
                e = ((mk[tile] >> (r * 8)) & 255u) ? 0.0f : e;
                psum += e;
                pk_[r] = (__bf16)e;
            }
            *(bf16x4*)&Ps[wave][l16][tile * 16 + l4 * 4] = pk_;
        }
        lsum += psum;
#pragma unroll
        for (int tile = 0; tile < 4; tile++) mk[tile] = mkn[tile];

        __builtin_amdgcn_s_setprio(1);
#pragma unroll
        for (int kk = 0; kk < 2; kk++) {
            bf16x8 pf = *(const bf16x8*)&Ps[wave][l16][kk * 32 + l4 * 8];
#pragma unroll
            for (int n = 0; n < 4; n++) {
                int row = n * 16 + l16;
                int colblk = (kk * 32 + l4 * 8) ^ ((row >> 3) << 3);
                bf16x8 vf = *(const bf16x8*)&Vt[grp][row][colblk];
                accT[n] = MFMA16(vf, pf, accT[n]);
            }
        }
        __builtin_amdgcn_s_setprio(0);
        __syncthreads();
    }

    lsum += __shfl_xor(lsum, 16);
    lsum += __shfl_xor(lsum, 32);

    float* exAcc = (float*)&Ks[0][0][0];
    float* exL = (float*)&Vt[0][0][0];
    if (grp == 1) {
#pragma unroll
        for (int n = 0; n < 4; n++)
            *(f32x4*)&exAcc[(wv * 16 + l16) * 68 + n * 16 + l4 * 4] = accT[n];
        if (l4 == 0) exL[wv * 16 + l16] = lsum;
    }
    __syncthreads();
    if (grp == 0) {
        int qi = wv * 16 + l16;
        float inv = 1.0f / (lsum + exL[qi]);
        __bf16* crow = ctx + ((size_t)(b * 1024 + q0 + l16) << 10) + h * 64;
#pragma unroll
        for (int n = 0; n < 4; n++) {
            f32x4 a1 = *(const f32x4*)&exAcc[qi * 68 + n * 16 + l4 * 4];
            bf16x4 o;
#pragma unroll
            for (int r = 0; r < 4; r++) o[r] = (__bf16)((accT[n][r] + a1[r]) * inv);
            *(bf16x4*)&crow[n * 16 + l4 * 4] = o;
        }
    }
}

// ---------------- launcher ----------------
extern "C" void kernel_launch(void* const* d_in, const int* in_sizes, int n_in,
                              void* d_out, int out_size, void* d_ws, size_t ws_size,
                              hipStream_t stream) {
    const float* x = (const float*)d_in[0];
    const float* memory_bank = (const float*)d_in[1];
    const unsigned char* attn_mask = (const unsigned char*)d_in[2];
    const float* ln1_g = (const float*)d_in[3];
    const float* ln1_b = (const float*)d_in[4];
    const float* Wq = (const float*)d_in[5];
    const float* Wk = (const float*)d_in[6];
    const float* Wv = (const float*)d_in[7];
    const float* Wo = (const float*)d_in[8];
    const float* ln2_g = (const float*)d_in[9];
    const float* ln2_b = (const float*)d_in[10];
    const float* W1 = (const float*)d_in[11];
    const float* b1 = (const float*)d_in[12];
    const float* W2 = (const float*)d_in[13];
    const float* b2 = (const float*)d_in[14];

    float* out = (float*)d_out;
    float* mem_out = out + 2097152;
    float* q_out = mem_out + 4 * 2097152;

    char* ws = (char*)d_ws;
    bool big = ws_size >= (89ull << 20);

    __bf16* PK = (__bf16*)ws;                        // [0,20) both modes
    __bf16* PV = (__bf16*)(ws + (20ull << 20));      // [20,40) both modes
    __bf16 *Pq, *Wq_t, *Wkv_t, *ctx, *membf = nullptr, *qbf = nullptr;
    __bf16 *Wo_t, *W1_t, *W2_t;
    __bf16* PVt = nullptr;
    __bf16* pacc = nullptr;
    float* plv = nullptr;
    unsigned int* mbits = nullptr;
    if (big) {
        membf = (__bf16*)(ws + (40ull << 20));       // [40,60)
        qbf = membf + (size_t)8192 * 1024;           // [56,60)
        Wq_t = (__bf16*)(ws + (60ull << 20));        // [60,62)
        Wkv_t = (__bf16*)(ws + (62ull << 20));       // [62,66)
        Pq = (__bf16*)(ws + (66ull << 20));          // [66,70)
        mbits = (unsigned int*)(ws + (70ull << 20)); // [70,70.25)
        Wo_t = (__bf16*)(ws + (71ull << 20));        // [71,73)  outside PK (attn-concurrent)
        W1_t = (__bf16*)(ws + (73ull << 20));        // [73,81)
        W2_t = (__bf16*)(ws + (81ull << 20));        // [81,89)
        PVt = (__bf16*)(ws + (40ull << 20));         // [40,60) after proj (membf dead)
        pacc = (__bf16*)(ws + (20ull << 20));        // [20,36) during attn (PV dead post-vtr)
        plv = (float*)(ws + (36ull << 20));          // [36,36.5)
        ctx = (__bf16*)(ws + (60ull << 20));         // [60,64) after attn (Wq_t/Wkv_t dead)
    } else {
        Pq = (__bf16*)(ws + (40ull << 20));          // [40,44)
        Wq_t = (__bf16*)(ws + (44ull << 20));        // [44,46)
        Wkv_t = (__bf16*)(ws + (46ull << 20));       // [46,50)
        ctx = (__bf16*)(ws + (44ull << 20));         // [44,48) after proj
        Wo_t = (__bf16*)ws;                          // [0,2)
        W1_t = (__bf16*)(ws + (2ull << 20));         // [2,10)
        W2_t = (__bf16*)(ws + (10ull << 20));        // [10,18)
    }
    // phase B (both modes)
    float* x2 = (float*)(ws + (18ull << 20));     // [18,26)
    __bf16* fln = (__bf16*)(ws + (26ull << 20));  // [26,30)
    __bf16* h1 = (__bf16*)(ws + (30ull << 20));   // [30,46)
    // Wo split-K4 partials (big): dead regions at that point
    float* wo_pc0 = (float*)ws;                   // [0,8)
    float* wo_pc1 = (float*)(ws + (8ull << 20));  // [8,16)
    float* wo_pc2 = (float*)(ws + (30ull << 20)); // [30,38)
    float* wo_pc3 = (float*)(ws + (38ull << 20)); // [38,46)
    // W2 split-K4 partials (big): PVt/Wkv_t/Pq/mbits/Wo_t/W1_t dead by then
    float* pc0 = (float*)(ws + (46ull << 20));    // [46,54)
    float* pc1 = (float*)(ws + (54ull << 20));    // [54,62)
    float* pc2 = (float*)(ws + (62ull << 20));    // [62,70)
    float* pc3 = (float*)(ws + (70ull << 20));    // [70,78)

    // 1. prep: copy bank (+bf16), LN1 (+bf16), early weight transposes, mask bitpack (big)
    prep_kernel<<<big ? 9216 : 7168, 256, 0, stream>>>(memory_bank, mem_out, membf, x,
                                                       ln1_g, ln1_b, q_out, qbf,
                                                       Wq, Wk, Wv, Wq_t, Wkv_t,
                                                       attn_mask, mbits);

    // 2. fused projections (split PK/PV)
    if (big)
        gemm_proj<true><<<1408, 256, 0, stream>>>(membf, Wkv_t, PK, PV, qbf, Wq_t, Pq);
    else
        gemm_proj<false><<<1408, 256, 0, stream>>>(mem_out, Wkv_t, PK, PV, q_out, Wq_t, Pq);

    // 3. attention (+ late weight transposes merged into the same launch, big mode)
    if (big) {
        vtr_kernel<<<2560, 256, 0, stream>>>(PV, PVt);
        attn_tr<<<10240, 256, 0, stream>>>(Pq, PK, PVt, mbits, pacc, plv,
                                           Wo, W1, W2, Wo_t, W1_t, W2_t);
        attn_comb<<<dim3(32, 8), 256, 0, stream>>>(pacc, plv, ctx);
    } else {
        attn_kernel<<<dim3(32, 16), 512, 0, stream>>>(Pq, PK, PV, attn_mask, ctx);
        tr_late<<<9216, 256, 0, stream>>>(Wo, W1, W2, Wo_t, W1_t, W2_t);
    }

    // 4. Wo + residual -> x2 (+ fused LN2 in big mode)
    if (big) {
        gemm_wo<<<512, 256, 0, stream>>>(ctx, Wo_t, wo_pc0, wo_pc1, wo_pc2, wo_pc3);
        comb_ln2<<<2048, 256, 0, stream>>>(wo_pc0, wo_pc1, wo_pc2, wo_pc3,
                                           x, ln2_g, ln2_b, x2, fln);
    } else {
        gemm_bt<1, true><<<128, 256, 0, stream>>>(ctx, Wo_t, x2, nullptr, x, 1024, 1024, 1.0f, 8);
        ln_kernel<<<2048, 256, 0, stream>>>(x2, ln2_g, ln2_b, fln);
    }
    // 5. FFN
    gemm_bt<2, true><<<512, 256, 0, stream>>>(fln, W1_t, h1, b1, nullptr, 4096, 1024, 1.0f, 32);
    if (big) {
        gemm_w2<<<512, 256, 0, stream>>>(h1, W2_t, pc0, pc1, pc2, pc3);
        comb_kernel<<<2048, 256, 0, stream>>>(pc0, pc1, pc2, pc3, b2, x2, out);
    } else {
        gemm_bt<3, true><<<128, 256, 0, stream>>>(h1, W2_t, out, b2, x2, 1024, 4096, 1.0f, 8);
    }
}